// Round 17
// baseline (130.004 us; speedup 1.0000x reference)
//
#include <hip/hip_runtime.h>
#include <hip/hip_bf16.h>

// All reference dtypes are float32 (verified R3): inputs const float*, output float*.

#define BATCH 2
#define NTOK 9216        // 96*96
#define CCH 64
#define DV 32
#define KS 6                          // key splits (per block; x4 waves -> eff 24)
#define KEYS_PER_BLOCK (NTOK / KS)    // 1536
#define KEYS_PER_WAVE (KEYS_PER_BLOCK / 4)  // 384 (per wave)
#define KT 32                         // keys per MFMA tile
#define NKT (KEYS_PER_WAVE / KT)      // 12 tiles per wave
#define ROWS (BATCH * NTOK)           // 18432
#define QTB (ROWS / 64)               // 288 query tiles (64 q per block)
#define NKTILE (NTOK / 32)            // 288 key tiles per batch
#define LOG2E 1.44269504088896340736f
#define PB 32                         // proj rows per block
#define XPAD 68                       // xS row stride (floats): conflict-free, 16B-aligned
#define ZTOT 152064                   // float4s to zero: l_acc+o_acc

typedef __attribute__((ext_vector_type(8))) short bf16x8;   // 8 bf16 (4 VGPRs)
typedef __attribute__((ext_vector_type(4))) float f32x4;    // MFMA C/D

__device__ __forceinline__ short f2bf(float x) {
    __hip_bfloat16 h = __float2bfloat16(x);   // RNE
    return *(short*)&h;
}
__device__ __forceinline__ float bf2f(short s) {
    unsigned u = ((unsigned)(unsigned short)s) << 16;
    return *(float*)&u;
}

// ---------------------------------------------------------------------------
// Kernel 1: projections -> MFMA-ready bf16 operands + zeroing of l/o_acc.
//  gx[row][32]: [g_hi(8) | g_lo(8) | g_hi(8) | 0]   (g pre-scaled by log2e)
//  fx[key][32]: [f_hi(8) | f_hi(8) | f_lo(8) | 0]
//  hTi[b][key_tile][v][k']: TILE-BLOCKED transposed H (R13-verified).
//   k' perm np(ni) = ((ni&15)>>2)*8 + (ni&3) + ((ni>>4)&1)*4 makes post-exp2
//   P registers directly usable as the PV A-frag (R8-verified).
// ---------------------------------------------------------------------------
__global__ __launch_bounds__(512) void proj_kernel(
    const float* __restrict__ x,
    const float* __restrict__ W1, const float* __restrict__ b1,
    const float* __restrict__ W2, const float* __restrict__ b2,
    const float* __restrict__ W3, const float* __restrict__ b3,
    short* __restrict__ fx, short* __restrict__ gx, short* __restrict__ hTi,
    float4* __restrict__ zbase)
{
    __shared__ float xS[PB * XPAD];      // 8.5 KB (padded rows, 272B stride)
    __shared__ short fgS[2][PB][32];     // 4 KB staging for fx, gx
    __shared__ short hS[32][PB + 2];     // 2.1 KB staging for hTi

    const int tid = threadIdx.x;
    const int r0  = blockIdx.x * PB;     // 32-row tile == one key tile

    // zero l_acc + o_acc: one float4 per thread, grid covers ZTOT
    {
        int zi = blockIdx.x * 512 + tid;
        if (zi < ZTOT) zbase[zi] = make_float4(0.f, 0.f, 0.f, 0.f);
    }

    // cooperative x load: 512 threads x float4 = 32 rows x 64 floats
    {
        const int row = tid >> 4, c4 = tid & 15;
        ((float4*)(xS + row * XPAD))[c4] =
            ((const float4*)(x + (size_t)(r0 + row) * CCH))[c4];
    }
    __syncthreads();

    // phase 1: f (tid<256) / g (tid>=256) — wave-uniform split
    {
        const int half = tid >> 8;            // 0: f, 1: g
        const int rr   = (tid & 255) >> 3;    // 0..31
        const int c    = tid & 7;             // 0..7
        const float4* xr4 = (const float4*)(xS + rr * XPAD);
        if (half == 0) {
            float acc = b1[c];
            #pragma unroll
            for (int k4 = 0; k4 < 16; ++k4) {
                float4 xv = xr4[k4];
                acc += xv.x * W1[(4*k4+0) * 8 + c] + xv.y * W1[(4*k4+1) * 8 + c]
                     + xv.z * W1[(4*k4+2) * 8 + c] + xv.w * W1[(4*k4+3) * 8 + c];
            }
            short hi = f2bf(acc);
            short lo = f2bf(acc - bf2f(hi));
            fgS[0][rr][c] = hi; fgS[0][rr][c + 8] = hi;
            fgS[0][rr][c + 16] = lo; fgS[0][rr][c + 24] = 0;
        } else {
            float acc = b2[c];
            #pragma unroll
            for (int k4 = 0; k4 < 16; ++k4) {
                float4 xv = xr4[k4];
                acc += xv.x * W2[(4*k4+0) * 8 + c] + xv.y * W2[(4*k4+1) * 8 + c]
                     + xv.z * W2[(4*k4+2) * 8 + c] + xv.w * W2[(4*k4+3) * 8 + c];
            }
            acc *= LOG2E;                 // fold log2(e) for exp2 inner loop
            short hi = f2bf(acc);
            short lo = f2bf(acc - bf2f(hi));
            fgS[1][rr][c] = hi; fgS[1][rr][c + 8] = lo;
            fgS[1][rr][c + 16] = hi; fgS[1][rr][c + 24] = 0;
        }
    }
    // phase 2: h — thread (c = tid&31, rbase = tid>>5) covers rows rbase, rbase+16
    {
        const int c = tid & 31;
        const int rbase = tid >> 5;
        #pragma unroll
        for (int s = 0; s < 2; ++s) {
            int rr = rbase + s * 16;
            const float4* xr4 = (const float4*)(xS + rr * XPAD);
            float acc = b3[c];
            #pragma unroll
            for (int k4 = 0; k4 < 16; ++k4) {
                float4 xv = xr4[k4];
                acc += xv.x * W3[(4*k4+0) * 32 + c] + xv.y * W3[(4*k4+1) * 32 + c]
                     + xv.z * W3[(4*k4+2) * 32 + c] + xv.w * W3[(4*k4+3) * 32 + c];
            }
            int np = ((rr & 15) >> 2) * 8 + (rr & 3) + ((rr >> 4) & 1) * 4;
            hS[c][np] = f2bf(acc);
        }
    }
    __syncthreads();

    // coalesced write-out (dwords)
    ((int*)(fx + (size_t)r0 * 32))[tid] = ((const int*)fgS[0])[tid];
    ((int*)(gx + (size_t)r0 * 32))[tid] = ((const int*)fgS[1])[tid];
    {
        const int b  = r0 / NTOK;
        const int n0 = r0 - b * NTOK;
        const int kt = n0 >> 5;               // key tile within batch
        const int c  = tid >> 4;              // v = 0..31
        const int d  = tid & 15;              // dword within 64B v-row
        ((int*)(hTi + ((size_t)(b * NKTILE + kt)) * 1024))[c * 16 + d] =
            ((const int*)&hS[c][0])[d];
    }
}

// ---------------------------------------------------------------------------
// Kernel 2: MFMA flash attention, Q=64/wave, 4 waves/block.
// R17: KS=6 (1728 blocks = 27 waves/CU offered, feeds the ~5-6/SIMD VGPR
// residency cap instead of KS=4's 4.5) + DEPTH-2 prefetch ring (fa/hb,
// next, next-next) giving ~2 full tiles (~800+ cyc) of L2-latency coverage
// vs the marginal ~300 cyc of the 1-deep prefetch.
// EXPPACK truncates to bf16 (R16: bias shared by P and l, cancels in o/l).
// QK transposed (A=f-ext, B=g-ext); post-exp2 P registers ARE the PV A-frag
// under the k' permutation (R8). Zero in-loop LDS; l via MFMA (B=ones).
// launch_bounds(256,4): VGPR cap 128 (NOT the R9/R10 min-waves>=8 spill trap).
// Grid: QTB*KS = 288*6 = 1728 blocks x 256 threads.
// ---------------------------------------------------------------------------
__global__ __launch_bounds__(256, 4) void attn_kernel(
    const short* __restrict__ fx, const short* __restrict__ gx,
    const short* __restrict__ hTi,
    float* __restrict__ l_acc, float* __restrict__ o_acc)
{
    __shared__ float red[64 * 33];            // epilogue-only, 8448 B

    const int tid  = threadIdx.x;
    const int wave = tid >> 6;                // 0..3
    const int lane = tid & 63;
    const int col  = lane & 15;
    const int quad = lane >> 4;

    const int blk = blockIdx.x;
    const int qt  = blk % QTB;                // query tile 0..287
    const int ks  = blk / QTB;                // key split 0..5
    const int b   = qt / (QTB / BATCH);       // batch
    const int qbase   = (qt % (QTB / BATCH)) * 64;
    const int rowbase = b * NTOK + qbase;

    // persistent B-operands for QK: g-ext for 4 query sub-tiles
    const bf16x8 agA = *(const bf16x8*)(gx + (size_t)(rowbase + col) * 32 + quad * 8);
    const bf16x8 agB = *(const bf16x8*)(gx + (size_t)(rowbase + 16 + col) * 32 + quad * 8);
    const bf16x8 agC = *(const bf16x8*)(gx + (size_t)(rowbase + 32 + col) * 32 + quad * 8);
    const bf16x8 agD = *(const bf16x8*)(gx + (size_t)(rowbase + 48 + col) * 32 + quad * 8);

    bf16x8 ones;
    #pragma unroll
    for (int j = 0; j < 8; ++j) ones[j] = (short)0x3F80;   // bf16 1.0

    f32x4 oA0 = {0,0,0,0}, oA1 = {0,0,0,0};
    f32x4 oB0 = {0,0,0,0}, oB1 = {0,0,0,0};
    f32x4 oC0 = {0,0,0,0}, oC1 = {0,0,0,0};
    f32x4 oD0 = {0,0,0,0}, oD1 = {0,0,0,0};
    f32x4 lfA = {0,0,0,0}, lfB = {0,0,0,0};
    f32x4 lfC = {0,0,0,0}, lfD = {0,0,0,0};
    const f32x4 zero4 = {0,0,0,0};

    const int kstart = ks * KEYS_PER_BLOCK + wave * KEYS_PER_WAVE;
    const short* fbase = fx + ((size_t)b * NTOK + kstart) * 32;
    const short* hbase = hTi + ((size_t)(b * NKTILE) + (kstart >> 5)) * 1024
                             + col * 32 + quad * 8;

    // depth-2 prefetch ring: current (fa/hb), next (fn/hn)
    bf16x8 fa0 = *(const bf16x8*)(fbase + (size_t)col * 32 + quad * 8);
    bf16x8 fa1 = *(const bf16x8*)(fbase + (size_t)(16 + col) * 32 + quad * 8);
    bf16x8 hb0 = *(const bf16x8*)(hbase);
    bf16x8 hb1 = *(const bf16x8*)(hbase + 512);
    bf16x8 fn0 = *(const bf16x8*)(fbase + (size_t)(KT + col) * 32 + quad * 8);
    bf16x8 fn1 = *(const bf16x8*)(fbase + (size_t)(KT + 16 + col) * 32 + quad * 8);
    bf16x8 hn0 = *(const bf16x8*)(hbase + 1024);
    bf16x8 hn1 = *(const bf16x8*)(hbase + 1024 + 512);

    union PU { int i[4]; bf16x8 v; };

    #define EXPPACK(T0, T1, P)                                                  \
    {                                                                           \
        float e0 = __builtin_amdgcn_exp2f(T0[0]), e1 = __builtin_amdgcn_exp2f(T0[1]); \
        float e2 = __builtin_amdgcn_exp2f(T0[2]), e3 = __builtin_amdgcn_exp2f(T0[3]); \
        float e4 = __builtin_amdgcn_exp2f(T1[0]), e5 = __builtin_amdgcn_exp2f(T1[1]); \
        float e6 = __builtin_amdgcn_exp2f(T1[2]), e7 = __builtin_amdgcn_exp2f(T1[3]); \
        P.i[0] = (int)__builtin_amdgcn_perm((unsigned)__float_as_int(e1),       \
                                            (unsigned)__float_as_int(e0), 0x07060302u); \
        P.i[1] = (int)__builtin_amdgcn_perm((unsigned)__float_as_int(e3),       \
                                            (unsigned)__float_as_int(e2), 0x07060302u); \
        P.i[2] = (int)__builtin_amdgcn_perm((unsigned)__float_as_int(e5),       \
                                            (unsigned)__float_as_int(e4), 0x07060302u); \
        P.i[3] = (int)__builtin_amdgcn_perm((unsigned)__float_as_int(e7),       \
                                            (unsigned)__float_as_int(e6), 0x07060302u); \
    }

    for (int t = 0; t < NKT; ++t) {
        // QK transposed for all 4 sub-tiles: lane holds S[q=col][k=quad*4+r]
        f32x4 tA0 = __builtin_amdgcn_mfma_f32_16x16x32_bf16(fa0, agA, zero4, 0, 0, 0);
        f32x4 tA1 = __builtin_amdgcn_mfma_f32_16x16x32_bf16(fa1, agA, zero4, 0, 0, 0);
        f32x4 tB0 = __builtin_amdgcn_mfma_f32_16x16x32_bf16(fa0, agB, zero4, 0, 0, 0);
        f32x4 tB1 = __builtin_amdgcn_mfma_f32_16x16x32_bf16(fa1, agB, zero4, 0, 0, 0);
        f32x4 tC0 = __builtin_amdgcn_mfma_f32_16x16x32_bf16(fa0, agC, zero4, 0, 0, 0);
        f32x4 tC1 = __builtin_amdgcn_mfma_f32_16x16x32_bf16(fa1, agC, zero4, 0, 0, 0);
        f32x4 tD0 = __builtin_amdgcn_mfma_f32_16x16x32_bf16(fa0, agD, zero4, 0, 0, 0);
        f32x4 tD1 = __builtin_amdgcn_mfma_f32_16x16x32_bf16(fa1, agD, zero4, 0, 0, 0);

        // prefetch tile t+2 (clamped; discarded on last iters)
        const int kn2 = (t + 2 < NKT) ? (t + 2) : 0;
        bf16x8 fp0 = *(const bf16x8*)(fbase + (size_t)(kn2 * KT + col) * 32 + quad * 8);
        bf16x8 fp1 = *(const bf16x8*)(fbase + (size_t)(kn2 * KT + 16 + col) * 32 + quad * 8);
        bf16x8 hp0 = *(const bf16x8*)(hbase + kn2 * 1024);
        bf16x8 hp1 = *(const bf16x8*)(hbase + kn2 * 1024 + 512);

        // exp2 + truncate-pack (P registers ARE the PV A-frag), then PV + l
        PU pA, pB, pC, pD;
        EXPPACK(tA0, tA1, pA)
        EXPPACK(tB0, tB1, pB)
        oA0 = __builtin_amdgcn_mfma_f32_16x16x32_bf16(pA.v, hb0, oA0, 0, 0, 0);
        oA1 = __builtin_amdgcn_mfma_f32_16x16x32_bf16(pA.v, hb1, oA1, 0, 0, 0);
        lfA = __builtin_amdgcn_mfma_f32_16x16x32_bf16(pA.v, ones, lfA, 0, 0, 0);
        oB0 = __builtin_amdgcn_mfma_f32_16x16x32_bf16(pB.v, hb0, oB0, 0, 0, 0);
        oB1 = __builtin_amdgcn_mfma_f32_16x16x32_bf16(pB.v, hb1, oB1, 0, 0, 0);
        lfB = __builtin_amdgcn_mfma_f32_16x16x32_bf16(pB.v, ones, lfB, 0, 0, 0);
        EXPPACK(tC0, tC1, pC)
        EXPPACK(tD0, tD1, pD)
        oC0 = __builtin_amdgcn_mfma_f32_16x16x32_bf16(pC.v, hb0, oC0, 0, 0, 0);
        oC1 = __builtin_amdgcn_mfma_f32_16x16x32_bf16(pC.v, hb1, oC1, 0, 0, 0);
        lfC = __builtin_amdgcn_mfma_f32_16x16x32_bf16(pC.v, ones, lfC, 0, 0, 0);
        oD0 = __builtin_amdgcn_mfma_f32_16x16x32_bf16(pD.v, hb0, oD0, 0, 0, 0);
        oD1 = __builtin_amdgcn_mfma_f32_16x16x32_bf16(pD.v, hb1, oD1, 0, 0, 0);
        lfD = __builtin_amdgcn_mfma_f32_16x16x32_bf16(pD.v, ones, lfD, 0, 0, 0);

        // rotate the prefetch ring
        fa0 = fn0; fa1 = fn1; hb0 = hn0; hb1 = hn1;
        fn0 = fp0; fn1 = fp1; hn0 = hp0; hn1 = hp1;
    }
    #undef EXPPACK

    // 3-round cross-wave merge in one 8.4 KB buffer: wave w publishes,
    // wave 0 accumulates into registers; then wave 0 issues global atomics.
    for (int w = 1; w < 4; ++w) {
        if (wave == w) {
            #pragma unroll
            for (int r = 0; r < 4; ++r) {
                int q = quad * 4 + r;
                red[(q)      * 33 + col]      = oA0[r];
                red[(q)      * 33 + 16 + col] = oA1[r];
                red[(q + 16) * 33 + col]      = oB0[r];
                red[(q + 16) * 33 + 16 + col] = oB1[r];
                red[(q + 32) * 33 + col]      = oC0[r];
                red[(q + 32) * 33 + 16 + col] = oC1[r];
                red[(q + 48) * 33 + col]      = oD0[r];
                red[(q + 48) * 33 + 16 + col] = oD1[r];
            }
            if (col == 0) {
                #pragma unroll
                for (int r = 0; r < 4; ++r) {
                    int q = quad * 4 + r;
                    red[(q)      * 33 + 32] = lfA[r];
                    red[(q + 16) * 33 + 32] = lfB[r];
                    red[(q + 32) * 33 + 32] = lfC[r];
                    red[(q + 48) * 33 + 32] = lfD[r];
                }
            }
        }
        __syncthreads();
        if (wave == 0) {
            #pragma unroll
            for (int r = 0; r < 4; ++r) {
                int q = quad * 4 + r;
                oA0[r] += red[(q)      * 33 + col];
                oA1[r] += red[(q)      * 33 + 16 + col];
                oB0[r] += red[(q + 16) * 33 + col];
                oB1[r] += red[(q + 16) * 33 + 16 + col];
                oC0[r] += red[(q + 32) * 33 + col];
                oC1[r] += red[(q + 32) * 33 + 16 + col];
                oD0[r] += red[(q + 48) * 33 + col];
                oD1[r] += red[(q + 48) * 33 + 16 + col];
                lfA[r] += red[(q)      * 33 + 32];
                lfB[r] += red[(q + 16) * 33 + 32];
                lfC[r] += red[(q + 32) * 33 + 32];
                lfD[r] += red[(q + 48) * 33 + 32];
            }
        }
        __syncthreads();
    }
    if (wave == 0) {
        #pragma unroll
        for (int r = 0; r < 4; ++r) {
            int q = quad * 4 + r;
            atomicAdd(&o_acc[(size_t)(rowbase + q)      * 32 + col],      oA0[r]);
            atomicAdd(&o_acc[(size_t)(rowbase + q)      * 32 + 16 + col], oA1[r]);
            atomicAdd(&o_acc[(size_t)(rowbase + q + 16) * 32 + col],      oB0[r]);
            atomicAdd(&o_acc[(size_t)(rowbase + q + 16) * 32 + 16 + col], oB1[r]);
            atomicAdd(&o_acc[(size_t)(rowbase + q + 32) * 32 + col],      oC0[r]);
            atomicAdd(&o_acc[(size_t)(rowbase + q + 32) * 32 + 16 + col], oC1[r]);
            atomicAdd(&o_acc[(size_t)(rowbase + q + 48) * 32 + col],      oD0[r]);
            atomicAdd(&o_acc[(size_t)(rowbase + q + 48) * 32 + 16 + col], oD1[r]);
        }
        if (col == 0) {
            #pragma unroll
            for (int r = 0; r < 4; ++r) {
                int q = quad * 4 + r;
                atomicAdd(&l_acc[rowbase + q],      lfA[r]);
                atomicAdd(&l_acc[rowbase + q + 16], lfB[r]);
                atomicAdd(&l_acc[rowbase + q + 32], lfC[r]);
                atomicAdd(&l_acc[rowbase + q + 48], lfD[r]);
            }
        }
    }
}

// ---------------------------------------------------------------------------
// Kernel 3: normalize + output projection + residual (fp32 weights).
// One wave per query: o[k] = o_acc/l ; out = gamma*(o@W4 + b4) + x
// ---------------------------------------------------------------------------
__global__ __launch_bounds__(256) void merge_kernel(
    const float* __restrict__ l_acc, const float* __restrict__ o_acc,
    const float* __restrict__ x,
    const float* __restrict__ W4, const float* __restrict__ b4,
    const float* __restrict__ gamma, float* __restrict__ out)
{
    __shared__ float oS[4][DV];
    int wave = threadIdx.x >> 6;
    int lane = threadIdx.x & 63;
    int row  = blockIdx.x * 4 + wave;     // < 18432 exactly

    float invL = 1.f / l_acc[row];
    if (lane < DV) {
        oS[wave][lane] = o_acc[(size_t)row * DV + lane] * invL;
    }
    __syncthreads();

    float dot = b4[lane];
    #pragma unroll
    for (int k = 0; k < DV; ++k) dot += oS[wave][k] * W4[k * 64 + lane];
    float gm  = gamma[0];
    float res = x[(size_t)row * 64 + lane];
    out[(size_t)row * 64 + lane] = gm * dot + res;
}

// ---------------------------------------------------------------------------
extern "C" void kernel_launch(void* const* d_in, const int* in_sizes, int n_in,
                              void* d_out, int out_size, void* d_ws, size_t ws_size,
                              hipStream_t stream) {
    const float* x     = (const float*)d_in[0];
    const float* W1    = (const float*)d_in[1];
    const float* b1    = (const float*)d_in[2];
    const float* W2    = (const float*)d_in[3];
    const float* b2    = (const float*)d_in[4];
    const float* W3    = (const float*)d_in[5];
    const float* b3    = (const float*)d_in[6];
    const float* W4    = (const float*)d_in[7];
    const float* b4    = (const float*)d_in[8];
    const float* gamma = (const float*)d_in[9];
    float* out = (float*)d_out;

    // Workspace: fx/gx/hTi bf16 (1.18 MB each) + l_acc + o_acc = 5.97 MB total
    short* fx    = (short*)d_ws;                       // 589824 shorts
    short* gx    = fx + (size_t)ROWS * 32;             // 589824 shorts
    short* hTi   = gx + (size_t)ROWS * 32;             // 589824 shorts
    float* l_acc = (float*)(hTi + (size_t)ROWS * 32);  // 18432 floats
    float* o_acc = l_acc + ROWS;                       // 589824 floats

    // proj (+ zeroing of l_acc/o_acc): 576 blocks x 512 threads
    proj_kernel<<<ROWS / PB, 512, 0, stream>>>(
        x, W1, b1, W2, b2, W3, b3, fx, gx, hTi, (float4*)l_acc);

    // attention: 288 query-tiles (64 q) x 6 key-splits = 1728 blocks x 4 waves
    attn_kernel<<<QTB * KS, 256, 0, stream>>>(fx, gx, hTi, l_acc, o_acc);

    // merge: 18432 queries / 4 waves per block
    merge_kernel<<<ROWS / 4, 256, 0, stream>>>(l_acc, o_acc, x, W4, b4, gamma, out);
}

// Round 18
// 128.592 us; speedup vs baseline: 1.0110x; 1.0110x over previous
//
#include <hip/hip_runtime.h>
#include <hip/hip_bf16.h>

// All reference dtypes are float32 (verified R3): inputs const float*, output float*.

#define BATCH 2
#define NTOK 9216        // 96*96
#define CCH 64
#define DV 32
#define KS 4                          // key splits (per block; x4 waves -> eff 16)
#define KEYS_PER_BLOCK (NTOK / KS)    // 2304
#define KEYS_PER_WAVE (KEYS_PER_BLOCK / 4)  // 576 (per wave)
#define KT 32                         // keys per MFMA tile
#define NKT (KEYS_PER_WAVE / KT)      // 18 tiles per wave
#define ROWS (BATCH * NTOK)           // 18432
#define QTB (ROWS / 64)               // 288 query tiles (64 q per block)
#define NKTILE (NTOK / 32)            // 288 key tiles per batch
#define LOG2E 1.44269504088896340736f
#define PB 32                         // proj rows per block
#define XPAD 68                       // xS row stride (floats): conflict-free, 16B-aligned
#define ZTOT 152064                   // float4s to zero: l_acc+o_acc

typedef __attribute__((ext_vector_type(8))) short bf16x8;   // 8 bf16 (4 VGPRs)
typedef __attribute__((ext_vector_type(4))) float f32x4;    // MFMA C/D

__device__ __forceinline__ short f2bf(float x) {
    __hip_bfloat16 h = __float2bfloat16(x);   // RNE
    return *(short*)&h;
}
__device__ __forceinline__ float bf2f(short s) {
    unsigned u = ((unsigned)(unsigned short)s) << 16;
    return *(float*)&u;
}

// ---------------------------------------------------------------------------
// Kernel 1: projections -> MFMA-ready bf16 operands + zeroing of l/o_acc.
//  gx[row][32]: [g_hi(8) | g_lo(8) | g_hi(8) | 0]   (g pre-scaled by log2e)
//  fx[key][32]: [f_hi(8) | f_hi(8) | f_lo(8) | 0]
//  hTi[b][key_tile][v][k']: TILE-BLOCKED transposed H (R13-verified).
//   k' perm np(ni) = ((ni&15)>>2)*8 + (ni&3) + ((ni>>4)&1)*4 makes post-exp2
//   P registers directly usable as the PV A-frag (R8-verified).
// ---------------------------------------------------------------------------
__global__ __launch_bounds__(512) void proj_kernel(
    const float* __restrict__ x,
    const float* __restrict__ W1, const float* __restrict__ b1,
    const float* __restrict__ W2, const float* __restrict__ b2,
    const float* __restrict__ W3, const float* __restrict__ b3,
    short* __restrict__ fx, short* __restrict__ gx, short* __restrict__ hTi,
    float4* __restrict__ zbase)
{
    __shared__ float xS[PB * XPAD];      // 8.5 KB (padded rows, 272B stride)
    __shared__ short fgS[2][PB][32];     // 4 KB staging for fx, gx
    __shared__ short hS[32][PB + 2];     // 2.1 KB staging for hTi

    const int tid = threadIdx.x;
    const int r0  = blockIdx.x * PB;     // 32-row tile == one key tile

    // zero l_acc + o_acc: one float4 per thread, grid covers ZTOT
    {
        int zi = blockIdx.x * 512 + tid;
        if (zi < ZTOT) zbase[zi] = make_float4(0.f, 0.f, 0.f, 0.f);
    }

    // cooperative x load: 512 threads x float4 = 32 rows x 64 floats
    {
        const int row = tid >> 4, c4 = tid & 15;
        ((float4*)(xS + row * XPAD))[c4] =
            ((const float4*)(x + (size_t)(r0 + row) * CCH))[c4];
    }
    __syncthreads();

    // phase 1: f (tid<256) / g (tid>=256) — wave-uniform split
    {
        const int half = tid >> 8;            // 0: f, 1: g
        const int rr   = (tid & 255) >> 3;    // 0..31
        const int c    = tid & 7;             // 0..7
        const float4* xr4 = (const float4*)(xS + rr * XPAD);
        if (half == 0) {
            float acc = b1[c];
            #pragma unroll
            for (int k4 = 0; k4 < 16; ++k4) {
                float4 xv = xr4[k4];
                acc += xv.x * W1[(4*k4+0) * 8 + c] + xv.y * W1[(4*k4+1) * 8 + c]
                     + xv.z * W1[(4*k4+2) * 8 + c] + xv.w * W1[(4*k4+3) * 8 + c];
            }
            short hi = f2bf(acc);
            short lo = f2bf(acc - bf2f(hi));
            fgS[0][rr][c] = hi; fgS[0][rr][c + 8] = hi;
            fgS[0][rr][c + 16] = lo; fgS[0][rr][c + 24] = 0;
        } else {
            float acc = b2[c];
            #pragma unroll
            for (int k4 = 0; k4 < 16; ++k4) {
                float4 xv = xr4[k4];
                acc += xv.x * W2[(4*k4+0) * 8 + c] + xv.y * W2[(4*k4+1) * 8 + c]
                     + xv.z * W2[(4*k4+2) * 8 + c] + xv.w * W2[(4*k4+3) * 8 + c];
            }
            acc *= LOG2E;                 // fold log2(e) for exp2 inner loop
            short hi = f2bf(acc);
            short lo = f2bf(acc - bf2f(hi));
            fgS[1][rr][c] = hi; fgS[1][rr][c + 8] = lo;
            fgS[1][rr][c + 16] = hi; fgS[1][rr][c + 24] = 0;
        }
    }
    // phase 2: h — thread (c = tid&31, rbase = tid>>5) covers rows rbase, rbase+16
    {
        const int c = tid & 31;
        const int rbase = tid >> 5;
        #pragma unroll
        for (int s = 0; s < 2; ++s) {
            int rr = rbase + s * 16;
            const float4* xr4 = (const float4*)(xS + rr * XPAD);
            float acc = b3[c];
            #pragma unroll
            for (int k4 = 0; k4 < 16; ++k4) {
                float4 xv = xr4[k4];
                acc += xv.x * W3[(4*k4+0) * 32 + c] + xv.y * W3[(4*k4+1) * 32 + c]
                     + xv.z * W3[(4*k4+2) * 32 + c] + xv.w * W3[(4*k4+3) * 32 + c];
            }
            int np = ((rr & 15) >> 2) * 8 + (rr & 3) + ((rr >> 4) & 1) * 4;
            hS[c][np] = f2bf(acc);
        }
    }
    __syncthreads();

    // coalesced write-out (dwords)
    ((int*)(fx + (size_t)r0 * 32))[tid] = ((const int*)fgS[0])[tid];
    ((int*)(gx + (size_t)r0 * 32))[tid] = ((const int*)fgS[1])[tid];
    {
        const int b  = r0 / NTOK;
        const int n0 = r0 - b * NTOK;
        const int kt = n0 >> 5;               // key tile within batch
        const int c  = tid >> 4;              // v = 0..31
        const int d  = tid & 15;              // dword within 64B v-row
        ((int*)(hTi + ((size_t)(b * NKTILE + kt)) * 1024))[c * 16 + d] =
            ((const int*)&hS[c][0])[d];
    }
}

// ---------------------------------------------------------------------------
// Kernel 2: MFMA flash attention, Q=64/wave, 4 waves/block (R16 config).
// R18: FULL UNROLL of the tile loop (NKT=18 compile-time). R17 showed the
// rolled loop forces ~32 v_mov/tile for the prefetch ring (~25% of VALU)
// and lets the scheduler collapse prefetch distance to zero (VGPR=64 =
// just-in-time reloads). Unrolling renames the ring instead of moving it
// and gives the scheduler a flat window to hoist loads a full tile early.
// EXPPACK truncates to bf16 (bias shared by P and l, cancels in o/l).
// QK transposed (A=f-ext, B=g-ext); post-exp2 P registers ARE the PV A-frag
// under the k' permutation (R8). Zero in-loop LDS; l via MFMA (B=ones).
// launch_bounds(256,4): VGPR cap 128 (NOT the R9/R10 min-waves>=8 spill trap).
// Grid: QTB*KS = 288*4 = 1152 blocks x 256 threads.
// ---------------------------------------------------------------------------
__global__ __launch_bounds__(256, 4) void attn_kernel(
    const short* __restrict__ fx, const short* __restrict__ gx,
    const short* __restrict__ hTi,
    float* __restrict__ l_acc, float* __restrict__ o_acc)
{
    __shared__ float red[64 * 33];            // epilogue-only, 8448 B

    const int tid  = threadIdx.x;
    const int wave = tid >> 6;                // 0..3
    const int lane = tid & 63;
    const int col  = lane & 15;
    const int quad = lane >> 4;

    const int blk = blockIdx.x;
    const int qt  = blk % QTB;                // query tile 0..287
    const int ks  = blk / QTB;                // key split 0..3
    const int b   = qt / (QTB / BATCH);       // batch
    const int qbase   = (qt % (QTB / BATCH)) * 64;
    const int rowbase = b * NTOK + qbase;

    // persistent B-operands for QK: g-ext for 4 query sub-tiles
    const bf16x8 agA = *(const bf16x8*)(gx + (size_t)(rowbase + col) * 32 + quad * 8);
    const bf16x8 agB = *(const bf16x8*)(gx + (size_t)(rowbase + 16 + col) * 32 + quad * 8);
    const bf16x8 agC = *(const bf16x8*)(gx + (size_t)(rowbase + 32 + col) * 32 + quad * 8);
    const bf16x8 agD = *(const bf16x8*)(gx + (size_t)(rowbase + 48 + col) * 32 + quad * 8);

    bf16x8 ones;
    #pragma unroll
    for (int j = 0; j < 8; ++j) ones[j] = (short)0x3F80;   // bf16 1.0

    f32x4 oA0 = {0,0,0,0}, oA1 = {0,0,0,0};
    f32x4 oB0 = {0,0,0,0}, oB1 = {0,0,0,0};
    f32x4 oC0 = {0,0,0,0}, oC1 = {0,0,0,0};
    f32x4 oD0 = {0,0,0,0}, oD1 = {0,0,0,0};
    f32x4 lfA = {0,0,0,0}, lfB = {0,0,0,0};
    f32x4 lfC = {0,0,0,0}, lfD = {0,0,0,0};
    const f32x4 zero4 = {0,0,0,0};

    const int kstart = ks * KEYS_PER_BLOCK + wave * KEYS_PER_WAVE;
    const short* fbase = fx + ((size_t)b * NTOK + kstart) * 32;
    const short* hbase = hTi + ((size_t)(b * NKTILE) + (kstart >> 5)) * 1024
                             + col * 32 + quad * 8;

    // preload tile 0
    bf16x8 fa0 = *(const bf16x8*)(fbase + (size_t)col * 32 + quad * 8);
    bf16x8 fa1 = *(const bf16x8*)(fbase + (size_t)(16 + col) * 32 + quad * 8);
    bf16x8 hb0 = *(const bf16x8*)(hbase);
    bf16x8 hb1 = *(const bf16x8*)(hbase + 512);

    union PU { int i[4]; bf16x8 v; };

    #define EXPPACK(T0, T1, P)                                                  \
    {                                                                           \
        float e0 = __builtin_amdgcn_exp2f(T0[0]), e1 = __builtin_amdgcn_exp2f(T0[1]); \
        float e2 = __builtin_amdgcn_exp2f(T0[2]), e3 = __builtin_amdgcn_exp2f(T0[3]); \
        float e4 = __builtin_amdgcn_exp2f(T1[0]), e5 = __builtin_amdgcn_exp2f(T1[1]); \
        float e6 = __builtin_amdgcn_exp2f(T1[2]), e7 = __builtin_amdgcn_exp2f(T1[3]); \
        P.i[0] = (int)__builtin_amdgcn_perm((unsigned)__float_as_int(e1),       \
                                            (unsigned)__float_as_int(e0), 0x07060302u); \
        P.i[1] = (int)__builtin_amdgcn_perm((unsigned)__float_as_int(e3),       \
                                            (unsigned)__float_as_int(e2), 0x07060302u); \
        P.i[2] = (int)__builtin_amdgcn_perm((unsigned)__float_as_int(e5),       \
                                            (unsigned)__float_as_int(e4), 0x07060302u); \
        P.i[3] = (int)__builtin_amdgcn_perm((unsigned)__float_as_int(e7),       \
                                            (unsigned)__float_as_int(e6), 0x07060302u); \
    }

    #pragma unroll
    for (int t = 0; t < NKT; ++t) {
        // QK transposed for all 4 sub-tiles: lane holds S[q=col][k=quad*4+r]
        f32x4 tA0 = __builtin_amdgcn_mfma_f32_16x16x32_bf16(fa0, agA, zero4, 0, 0, 0);
        f32x4 tA1 = __builtin_amdgcn_mfma_f32_16x16x32_bf16(fa1, agA, zero4, 0, 0, 0);
        f32x4 tB0 = __builtin_amdgcn_mfma_f32_16x16x32_bf16(fa0, agB, zero4, 0, 0, 0);
        f32x4 tB1 = __builtin_amdgcn_mfma_f32_16x16x32_bf16(fa1, agB, zero4, 0, 0, 0);
        f32x4 tC0 = __builtin_amdgcn_mfma_f32_16x16x32_bf16(fa0, agC, zero4, 0, 0, 0);
        f32x4 tC1 = __builtin_amdgcn_mfma_f32_16x16x32_bf16(fa1, agC, zero4, 0, 0, 0);
        f32x4 tD0 = __builtin_amdgcn_mfma_f32_16x16x32_bf16(fa0, agD, zero4, 0, 0, 0);
        f32x4 tD1 = __builtin_amdgcn_mfma_f32_16x16x32_bf16(fa1, agD, zero4, 0, 0, 0);

        // prefetch tile t+1 (compile-time clamp; discarded on last iter)
        const int kn = (t + 1 < NKT) ? (t + 1) : 0;
        bf16x8 nf0 = *(const bf16x8*)(fbase + (size_t)(kn * KT + col) * 32 + quad * 8);
        bf16x8 nf1 = *(const bf16x8*)(fbase + (size_t)(kn * KT + 16 + col) * 32 + quad * 8);
        bf16x8 nh0 = *(const bf16x8*)(hbase + kn * 1024);
        bf16x8 nh1 = *(const bf16x8*)(hbase + kn * 1024 + 512);

        // exp2 + truncate-pack (P registers ARE the PV A-frag), then PV + l
        PU pA, pB, pC, pD;
        EXPPACK(tA0, tA1, pA)
        EXPPACK(tB0, tB1, pB)
        oA0 = __builtin_amdgcn_mfma_f32_16x16x32_bf16(pA.v, hb0, oA0, 0, 0, 0);
        oA1 = __builtin_amdgcn_mfma_f32_16x16x32_bf16(pA.v, hb1, oA1, 0, 0, 0);
        lfA = __builtin_amdgcn_mfma_f32_16x16x32_bf16(pA.v, ones, lfA, 0, 0, 0);
        oB0 = __builtin_amdgcn_mfma_f32_16x16x32_bf16(pB.v, hb0, oB0, 0, 0, 0);
        oB1 = __builtin_amdgcn_mfma_f32_16x16x32_bf16(pB.v, hb1, oB1, 0, 0, 0);
        lfB = __builtin_amdgcn_mfma_f32_16x16x32_bf16(pB.v, ones, lfB, 0, 0, 0);
        EXPPACK(tC0, tC1, pC)
        EXPPACK(tD0, tD1, pD)
        oC0 = __builtin_amdgcn_mfma_f32_16x16x32_bf16(pC.v, hb0, oC0, 0, 0, 0);
        oC1 = __builtin_amdgcn_mfma_f32_16x16x32_bf16(pC.v, hb1, oC1, 0, 0, 0);
        lfC = __builtin_amdgcn_mfma_f32_16x16x32_bf16(pC.v, ones, lfC, 0, 0, 0);
        oD0 = __builtin_amdgcn_mfma_f32_16x16x32_bf16(pD.v, hb0, oD0, 0, 0, 0);
        oD1 = __builtin_amdgcn_mfma_f32_16x16x32_bf16(pD.v, hb1, oD1, 0, 0, 0);
        lfD = __builtin_amdgcn_mfma_f32_16x16x32_bf16(pD.v, ones, lfD, 0, 0, 0);

        // unrolled -> these become SSA renames, not v_mov chains
        fa0 = nf0; fa1 = nf1; hb0 = nh0; hb1 = nh1;
    }
    #undef EXPPACK

    // 3-round cross-wave merge in one 8.4 KB buffer: wave w publishes,
    // wave 0 accumulates into registers; then wave 0 issues global atomics.
    for (int w = 1; w < 4; ++w) {
        if (wave == w) {
            #pragma unroll
            for (int r = 0; r < 4; ++r) {
                int q = quad * 4 + r;
                red[(q)      * 33 + col]      = oA0[r];
                red[(q)      * 33 + 16 + col] = oA1[r];
                red[(q + 16) * 33 + col]      = oB0[r];
                red[(q + 16) * 33 + 16 + col] = oB1[r];
                red[(q + 32) * 33 + col]      = oC0[r];
                red[(q + 32) * 33 + 16 + col] = oC1[r];
                red[(q + 48) * 33 + col]      = oD0[r];
                red[(q + 48) * 33 + 16 + col] = oD1[r];
            }
            if (col == 0) {
                #pragma unroll
                for (int r = 0; r < 4; ++r) {
                    int q = quad * 4 + r;
                    red[(q)      * 33 + 32] = lfA[r];
                    red[(q + 16) * 33 + 32] = lfB[r];
                    red[(q + 32) * 33 + 32] = lfC[r];
                    red[(q + 48) * 33 + 32] = lfD[r];
                }
            }
        }
        __syncthreads();
        if (wave == 0) {
            #pragma unroll
            for (int r = 0; r < 4; ++r) {
                int q = quad * 4 + r;
                oA0[r] += red[(q)      * 33 + col];
                oA1[r] += red[(q)      * 33 + 16 + col];
                oB0[r] += red[(q + 16) * 33 + col];
                oB1[r] += red[(q + 16) * 33 + 16 + col];
                oC0[r] += red[(q + 32) * 33 + col];
                oC1[r] += red[(q + 32) * 33 + 16 + col];
                oD0[r] += red[(q + 48) * 33 + col];
                oD1[r] += red[(q + 48) * 33 + 16 + col];
                lfA[r] += red[(q)      * 33 + 32];
                lfB[r] += red[(q + 16) * 33 + 32];
                lfC[r] += red[(q + 32) * 33 + 32];
                lfD[r] += red[(q + 48) * 33 + 32];
            }
        }
        __syncthreads();
    }
    if (wave == 0) {
        #pragma unroll
        for (int r = 0; r < 4; ++r) {
            int q = quad * 4 + r;
            atomicAdd(&o_acc[(size_t)(rowbase + q)      * 32 + col],      oA0[r]);
            atomicAdd(&o_acc[(size_t)(rowbase + q)      * 32 + 16 + col], oA1[r]);
            atomicAdd(&o_acc[(size_t)(rowbase + q + 16) * 32 + col],      oB0[r]);
            atomicAdd(&o_acc[(size_t)(rowbase + q + 16) * 32 + 16 + col], oB1[r]);
            atomicAdd(&o_acc[(size_t)(rowbase + q + 32) * 32 + col],      oC0[r]);
            atomicAdd(&o_acc[(size_t)(rowbase + q + 32) * 32 + 16 + col], oC1[r]);
            atomicAdd(&o_acc[(size_t)(rowbase + q + 48) * 32 + col],      oD0[r]);
            atomicAdd(&o_acc[(size_t)(rowbase + q + 48) * 32 + 16 + col], oD1[r]);
        }
        if (col == 0) {
            #pragma unroll
            for (int r = 0; r < 4; ++r) {
                int q = quad * 4 + r;
                atomicAdd(&l_acc[rowbase + q],      lfA[r]);
                atomicAdd(&l_acc[rowbase + q + 16], lfB[r]);
                atomicAdd(&l_acc[rowbase + q + 32], lfC[r]);
                atomicAdd(&l_acc[rowbase + q + 48], lfD[r]);
            }
        }
    }
}

// ---------------------------------------------------------------------------
// Kernel 3: normalize + output projection + residual (fp32 weights).
// One wave per query: o[k] = o_acc/l ; out = gamma*(o@W4 + b4) + x
// ---------------------------------------------------------------------------
__global__ __launch_bounds__(256) void merge_kernel(
    const float* __restrict__ l_acc, const float* __restrict__ o_acc,
    const float* __restrict__ x,
    const float* __restrict__ W4, const float* __restrict__ b4,
    const float* __restrict__ gamma, float* __restrict__ out)
{
    __shared__ float oS[4][DV];
    int wave = threadIdx.x >> 6;
    int lane = threadIdx.x & 63;
    int row  = blockIdx.x * 4 + wave;     // < 18432 exactly

    float invL = 1.f / l_acc[row];
    if (lane < DV) {
        oS[wave][lane] = o_acc[(size_t)row * DV + lane] * invL;
    }
    __syncthreads();

    float dot = b4[lane];
    #pragma unroll
    for (int k = 0; k < DV; ++k) dot += oS[wave][k] * W4[k * 64 + lane];
    float gm  = gamma[0];
    float res = x[(size_t)row * 64 + lane];
    out[(size_t)row * 64 + lane] = gm * dot + res;
}

// ---------------------------------------------------------------------------
extern "C" void kernel_launch(void* const* d_in, const int* in_sizes, int n_in,
                              void* d_out, int out_size, void* d_ws, size_t ws_size,
                              hipStream_t stream) {
    const float* x     = (const float*)d_in[0];
    const float* W1    = (const float*)d_in[1];
    const float* b1    = (const float*)d_in[2];
    const float* W2    = (const float*)d_in[3];
    const float* b2    = (const float*)d_in[4];
    const float* W3    = (const float*)d_in[5];
    const float* b3    = (const float*)d_in[6];
    const float* W4    = (const float*)d_in[7];
    const float* b4    = (const float*)d_in[8];
    const float* gamma = (const float*)d_in[9];
    float* out = (float*)d_out;

    // Workspace: fx/gx/hTi bf16 (1.18 MB each) + l_acc + o_acc = 5.97 MB total
    short* fx    = (short*)d_ws;                       // 589824 shorts
    short* gx    = fx + (size_t)ROWS * 32;             // 589824 shorts
    short* hTi   = gx + (size_t)ROWS * 32;             // 589824 shorts
    float* l_acc = (float*)(hTi + (size_t)ROWS * 32);  // 18432 floats
    float* o_acc = l_acc + ROWS;                       // 589824 floats

    // proj (+ zeroing of l_acc/o_acc): 576 blocks x 512 threads
    proj_kernel<<<ROWS / PB, 512, 0, stream>>>(
        x, W1, b1, W2, b2, W3, b3, fx, gx, hTi, (float4*)l_acc);

    // attention: 288 query-tiles (64 q) x 4 key-splits = 1152 blocks x 4 waves
    attn_kernel<<<QTB * KS, 256, 0, stream>>>(fx, gx, hTi, l_acc, o_acc);

    // merge: 18432 queries / 4 waves per block
    merge_kernel<<<ROWS / 4, 256, 0, stream>>>(l_acc, o_acc, x, W4, b4, gamma, out);
}